// Round 13
// baseline (748.357 us; speedup 1.0000x reference)
//
#include <hip/hip_runtime.h>

// ---------------------------------------------------------------------------
// GCN 2-layer. N=50000, E=800000, F: 128 -> 128 -> 64.
// R8-R11: wave-per-node agg pinned at 58us, FETCH 188MB = 7.3x h-table ->
//   XCD L2 duplication (each of 8 private L2s pulls ~whole table), drained
//   at ~3.3TB/s random-128B fill ceiling.
// R12: blockIdx%8 slicing FAILED (mapping wrong + interleaved-layout line
//   sharing + 16-group fold VALU blowup): 140us.
// R13: exact pinning via s_getreg(HW_REG_XCC_ID) + persistent blocks +
//   8 atomic work queues (steal on imbalance; any block may run any task ->
//   correctness independent of scheduling). h stored SLICED
//   [slice][node][16] (GEMM writes that layout). Per-XCD footprint 3.2MB
//   (agg1) / 1.6MB (agg2) -> gathers become L2 hits. 4 edge-groups x 16
//   scalar lanes: fold = 2 shfl-adds.
// ---------------------------------------------------------------------------

#define N_NODES 50000
#define N_EDGES 800000

// workspace layout (bytes)
static constexpr size_t OFF_DEG  = 0;         // int[50000]
static constexpr size_t OFF_CUR  = 200192;    // int[50000]
static constexpr size_t OFF_QC1  = 400192;    // int[8]  agg1 queues
static constexpr size_t OFF_QC2  = 400256;    // int[8]  agg2 queues
static constexpr size_t OFF_ROW  = 400384;    // int[50001]
static constexpr size_t OFF_BS   = 600576;    // int[256]
static constexpr size_t OFF_DINV = 601600;    // float[50000]
static constexpr size_t OFF_SW   = 801792;    // int2[800000] {src, w_bits}
static constexpr size_t OFF_H1   = 7201792;   // sliced h: [S][50000][16] (reused as h2s)
static constexpr size_t OFF_OUT1 = 32801792;  // float[50000*128]
// total ~58.4 MB  (memset zeroes [0, OFF_ROW) each launch: deg+cursor+queues)

__global__ __launch_bounds__(256) void count_deg_k(const int* __restrict__ ei,
                                                   int* __restrict__ deg) {
    int e = blockIdx.x * 256 + threadIdx.x;
    if (e < N_EDGES) {
        int d = ei[N_EDGES + e];
        if ((unsigned)d < N_NODES) atomicAdd(&deg[d], 1);
    }
}

__global__ __launch_bounds__(256) void scan1_k(const int* __restrict__ deg,
                                               int* __restrict__ row_start,
                                               int* __restrict__ bsums,
                                               float* __restrict__ dinv) {
    __shared__ int sm[256];
    int tid = threadIdx.x;
    int i = blockIdx.x * 256 + tid;
    int v = (i < N_NODES) ? deg[i] : 0;
    if (i < N_NODES) dinv[i] = rsqrtf((float)(v + 1));
    sm[tid] = v;
    __syncthreads();
    #pragma unroll
    for (int off = 1; off < 256; off <<= 1) {
        int t = (tid >= off) ? sm[tid - off] : 0;
        __syncthreads();
        sm[tid] += t;
        __syncthreads();
    }
    if (i < N_NODES) row_start[i] = sm[tid] - v;
    if (tid == 255) bsums[blockIdx.x] = sm[255];
}

__global__ __launch_bounds__(256) void scan2_k(int* __restrict__ bsums, int nb) {
    __shared__ int sm[256];
    int tid = threadIdx.x;
    int v = (tid < nb) ? bsums[tid] : 0;
    sm[tid] = v;
    __syncthreads();
    #pragma unroll
    for (int off = 1; off < 256; off <<= 1) {
        int t = (tid >= off) ? sm[tid - off] : 0;
        __syncthreads();
        sm[tid] += t;
        __syncthreads();
    }
    if (tid < nb) bsums[tid] = sm[tid] - v;
}

__global__ __launch_bounds__(256) void scan3_k(int* __restrict__ row_start,
                                               const int* __restrict__ bsums) {
    int i = blockIdx.x * 256 + threadIdx.x;
    if (i < N_NODES) row_start[i] += bsums[blockIdx.x];
    if (i == 0) row_start[N_NODES] = N_EDGES;
}

__global__ __launch_bounds__(256) void fill_k(const int* __restrict__ ei,
                                              const int* __restrict__ row_start,
                                              int* __restrict__ cursor,
                                              const float* __restrict__ dinv,
                                              int2* __restrict__ csr_sw) {
    int e = blockIdx.x * 256 + threadIdx.x;
    if (e < N_EDGES) {
        int s = ei[e];
        int d = ei[N_EDGES + e];
        if ((unsigned)d < N_NODES && (unsigned)s < N_NODES) {
            int pos = row_start[d] + atomicAdd(&cursor[d], 1);
            if ((unsigned)pos < N_EDGES)
                csr_sw[pos] = make_int2(s, __float_as_int(dinv[s]));
        }
    }
}

// ---------------------------------------------------------------------------
// fp32 GEMM, whole-B-in-LDS; C written in SLICED layout [slice][node][16].
// ---------------------------------------------------------------------------
template <int N>
__global__ __launch_bounds__(256, 4) void gemm_blds(const float* __restrict__ A,
                                                    const float* __restrict__ B,
                                                    float* __restrict__ Cs, int M) {
    constexpr int K = 128, BM = 64, BN = 64, PAD = 4;
    __shared__ float Bs[K][BN + PAD];

    const int tid = threadIdx.x;
    const int nBase = blockIdx.y * BN;

    #pragma unroll
    for (int p = 0; p < 8; ++p) {
        int fi = tid + p * 256;
        int row = fi >> 4;
        int c4 = (fi & 15) * 4;
        float4 t = *(const float4*)&B[(size_t)row * N + nBase + c4];
        *(float4*)&Bs[row][c4] = t;
    }
    __syncthreads();

    const int tx = tid & 15, ty = tid >> 4;
    const int m0 = blockIdx.x * BM + ty * 4;
    const int n0 = tx * 4;

    const float* A0 = A + (size_t)(m0 + 0 < M ? m0 + 0 : M - 1) * K;
    const float* A1 = A + (size_t)(m0 + 1 < M ? m0 + 1 : M - 1) * K;
    const float* A2 = A + (size_t)(m0 + 2 < M ? m0 + 2 : M - 1) * K;
    const float* A3 = A + (size_t)(m0 + 3 < M ? m0 + 3 : M - 1) * K;

    float acc[4][4] = {};

    #pragma unroll 4
    for (int kq = 0; kq < K / 4; ++kq) {
        float4 a0 = *(const float4*)&A0[kq * 4];
        float4 a1 = *(const float4*)&A1[kq * 4];
        float4 a2 = *(const float4*)&A2[kq * 4];
        float4 a3 = *(const float4*)&A3[kq * 4];
        #pragma unroll
        for (int kk = 0; kk < 4; ++kk) {
            int k = kq * 4 + kk;
            float4 bv = *(const float4*)&Bs[k][n0];
            float av0 = kk == 0 ? a0.x : kk == 1 ? a0.y : kk == 2 ? a0.z : a0.w;
            float av1 = kk == 0 ? a1.x : kk == 1 ? a1.y : kk == 2 ? a1.z : a1.w;
            float av2 = kk == 0 ? a2.x : kk == 1 ? a2.y : kk == 2 ? a2.z : a2.w;
            float av3 = kk == 0 ? a3.x : kk == 1 ? a3.y : kk == 2 ? a3.z : a3.w;
            acc[0][0] = fmaf(av0, bv.x, acc[0][0]);
            acc[0][1] = fmaf(av0, bv.y, acc[0][1]);
            acc[0][2] = fmaf(av0, bv.z, acc[0][2]);
            acc[0][3] = fmaf(av0, bv.w, acc[0][3]);
            acc[1][0] = fmaf(av1, bv.x, acc[1][0]);
            acc[1][1] = fmaf(av1, bv.y, acc[1][1]);
            acc[1][2] = fmaf(av1, bv.z, acc[1][2]);
            acc[1][3] = fmaf(av1, bv.w, acc[1][3]);
            acc[2][0] = fmaf(av2, bv.x, acc[2][0]);
            acc[2][1] = fmaf(av2, bv.y, acc[2][1]);
            acc[2][2] = fmaf(av2, bv.z, acc[2][2]);
            acc[2][3] = fmaf(av2, bv.w, acc[2][3]);
            acc[3][0] = fmaf(av3, bv.x, acc[3][0]);
            acc[3][1] = fmaf(av3, bv.y, acc[3][1]);
            acc[3][2] = fmaf(av3, bv.z, acc[3][2]);
            acc[3][3] = fmaf(av3, bv.w, acc[3][3]);
        }
    }

    // sliced write: col block n0 (aligned 4) lies in slice (nBase+n0)>>4
    const int col0 = nBase + n0;
    const int slice = col0 >> 4;
    const int c15 = col0 & 15;
    #pragma unroll
    for (int i = 0; i < 4; ++i) {
        int row = blockIdx.x * BM + ty * 4 + i;
        if (row < M) {
            *(float4*)&Cs[(((size_t)slice * N_NODES + row) << 4) + c15] =
                make_float4(acc[i][0], acc[i][1], acc[i][2], acc[i][3]);
        }
    }
}

// ---------------------------------------------------------------------------
// XCD-pinned sliced aggregation (persistent, work-stealing).
// Queue q -> slice q%SLICES, node-range (q/SLICES) of N/(8/SLICES).
// Wave: 4 edge-groups x 16 scalar lanes (col c of the 16-col slice).
// out[v][slice] = dv*(sum_e w_e h_s[s][slice] + dv h_s[v][slice]) + b
// ---------------------------------------------------------------------------
template <int F, int SLICES, bool RELU>
__global__ __launch_bounds__(256) void agg_sliced_k(const float* __restrict__ h_s,
                                                    const float* __restrict__ dinv,
                                                    const int* __restrict__ row_start,
                                                    const int2* __restrict__ csr_sw,
                                                    const float* __restrict__ bias,
                                                    float* __restrict__ out,
                                                    int* __restrict__ qctr) {
    constexpr int NQ = 8;
    constexpr int CH = 64;                         // nodes per task
    constexpr int HALVES = NQ / SLICES;            // 1 or 2
    constexpr int NPQ = N_NODES / HALVES;          // nodes per queue
    constexpr int NCHUNK = (NPQ + CH - 1) / CH;

    __shared__ int sm_chunk;

    int xcd;
    asm volatile("s_getreg_b32 %0, hwreg(HW_REG_XCC_ID)" : "=s"(xcd));
    xcd &= 7;

    const int wv = threadIdx.x >> 6;
    const int lane = threadIdx.x & 63;
    const int g = lane >> 4;      // edge group 0..3
    const int c = lane & 15;      // col within slice

    for (int qi = 0; qi < NQ; ++qi) {
        const int q = (xcd + qi) & (NQ - 1);
        const int slice = q % SLICES;
        const int nbase = (q / SLICES) * NPQ;
        const float* hS = h_s + ((size_t)slice * N_NODES << 4) + c;
        const float bc = bias[slice * 16 + c];

        while (true) {
            if (threadIdx.x == 0) sm_chunk = atomicAdd(&qctr[q], 1);
            __syncthreads();
            const int chunk = sm_chunk;
            __syncthreads();
            if (chunk >= NCHUNK) break;

            const int vend = min(nbase + (chunk + 1) * CH, nbase + NPQ);
            for (int v = nbase + chunk * CH + wv; v < vend; v += 4) {
                const float dv = dinv[v];
                float acc = (g == 0) ? dv * hS[(size_t)v << 4] : 0.f;
                const int e0 = row_start[v], e1 = row_start[v + 1];
                for (int e = e0; e < e1; e += 64) {
                    const int cnt = min(64, e1 - e);
                    const int c1 = cnt - 1;
                    int s = 0; float w = 0.f;
                    if (lane < cnt) {
                        int2 p = csr_sw[e + lane];
                        s = p.x; w = __int_as_float(p.y);
                    }
                    for (int j = 0; j < cnt; j += 4) {
                        const int idx = j + g;
                        const int i0 = min(idx, c1);
                        const int ss = __shfl(s, i0);
                        float ww = __shfl(w, i0);
                        if (idx >= cnt) ww = 0.f;
                        acc = fmaf(ww, hS[(size_t)ss << 4], acc);
                    }
                }
                acc += __shfl(acc, lane + 32);
                acc += __shfl(acc, lane + 16);
                if (g == 0) {
                    float o = dv * acc + bc;
                    if (RELU) o = fmaxf(o, 0.f);
                    out[(size_t)v * F + slice * 16 + c] = o;
                }
            }
        }
    }
}

extern "C" void kernel_launch(void* const* d_in, const int* in_sizes, int n_in,
                              void* d_out, int out_size, void* d_ws, size_t ws_size,
                              hipStream_t stream) {
    const float* x        = (const float*)d_in[0];   // [50000,128]
    const float* W1       = (const float*)d_in[1];   // [128,128]
    const float* b1       = (const float*)d_in[2];   // [128]
    const float* W2       = (const float*)d_in[3];   // [128,64]
    const float* b2       = (const float*)d_in[4];   // [64]
    const int*   ei       = (const int*)d_in[5];     // [2,800000] int32
    float* out = (float*)d_out;                      // [50000,64]

    char* ws = (char*)d_ws;
    int*   deg       = (int*)(ws + OFF_DEG);
    int*   cursor    = (int*)(ws + OFF_CUR);
    int*   qc1       = (int*)(ws + OFF_QC1);
    int*   qc2       = (int*)(ws + OFF_QC2);
    int*   row_start = (int*)(ws + OFF_ROW);
    int*   bsums     = (int*)(ws + OFF_BS);
    float* dinv      = (float*)(ws + OFF_DINV);
    int2*  csr_sw    = (int2*)(ws + OFF_SW);
    float* h1s       = (float*)(ws + OFF_H1);
    float* out1      = (float*)(ws + OFF_OUT1);
    float* h2s       = (float*)(ws + OFF_H1);  // reuse

    // zero deg + cursor + both queue-counter sets
    hipMemsetAsync(ws + OFF_DEG, 0, OFF_ROW - OFF_DEG, stream);

    const int nbE = (N_EDGES + 255) / 256;
    const int nbN = (N_NODES + 255) / 256;

    count_deg_k<<<nbE, 256, 0, stream>>>(ei, deg);
    scan1_k<<<nbN, 256, 0, stream>>>(deg, row_start, bsums, dinv);
    scan2_k<<<1, 256, 0, stream>>>(bsums, nbN);
    scan3_k<<<nbN, 256, 0, stream>>>(row_start, bsums);
    fill_k<<<nbE, 256, 0, stream>>>(ei, row_start, cursor, dinv, csr_sw);

    const int mBlocks = (N_NODES + 63) / 64;   // 782
    const int PERSIST = 2048;                  // 8 blocks/CU

    gemm_blds<128><<<dim3(mBlocks, 2), 256, 0, stream>>>(x, W1, h1s, N_NODES);
    agg_sliced_k<128, 8, true><<<PERSIST, 256, 0, stream>>>(h1s, dinv, row_start, csr_sw, b1, out1, qc1);
    gemm_blds<64><<<dim3(mBlocks, 1), 256, 0, stream>>>(out1, W2, h2s, N_NODES);
    agg_sliced_k<64, 4, false><<<PERSIST, 256, 0, stream>>>(h2s, dinv, row_start, csr_sw, b2, out, qc2);
}

// Round 14
// 725.901 us; speedup vs baseline: 1.0309x; 1.0309x over previous
//
#include <hip/hip_runtime.h>

// ---------------------------------------------------------------------------
// GCN 2-layer. N=50000, E=800000, F: 128 -> 128 -> 64.
// R8-R11: wave-per-node agg pinned at 58us, FETCH 188MB = 7.3x h-table ->
//   per-XCD L2 duplication, drained at ~3.3TB/s random-fill ceiling.
// R13: XCC-pinned queues + sliced [slice][node][16] h layout: FETCH 188->70MB
//   (locality CONFIRMED) but 356us: un-unrollable serial shfl->gather->fma
//   chain = 1 L2 gather in flight, x8 per-slice edge re-processing.
// R14: same structure + manual 4-deep MLP (16-edge stride fast path, 4
//   independent gathers in flight per lane). L2 gather floor ~13us aggregate.
// ---------------------------------------------------------------------------

#define N_NODES 50000
#define N_EDGES 800000

// workspace layout (bytes)
static constexpr size_t OFF_DEG  = 0;         // int[50000]
static constexpr size_t OFF_CUR  = 200192;    // int[50000]
static constexpr size_t OFF_QC1  = 400192;    // int[8]  agg1 queues
static constexpr size_t OFF_QC2  = 400256;    // int[8]  agg2 queues
static constexpr size_t OFF_ROW  = 400384;    // int[50001]
static constexpr size_t OFF_BS   = 600576;    // int[256]
static constexpr size_t OFF_DINV = 601600;    // float[50000]
static constexpr size_t OFF_SW   = 801792;    // int2[800000] {src, w_bits}
static constexpr size_t OFF_H1   = 7201792;   // sliced h: [S][50000][16]
static constexpr size_t OFF_OUT1 = 32801792;  // float[50000*128]
// total ~58.4 MB  (memset zeroes [0, OFF_ROW): deg+cursor+queues)

__global__ __launch_bounds__(256) void count_deg_k(const int* __restrict__ ei,
                                                   int* __restrict__ deg) {
    int e = blockIdx.x * 256 + threadIdx.x;
    if (e < N_EDGES) {
        int d = ei[N_EDGES + e];
        if ((unsigned)d < N_NODES) atomicAdd(&deg[d], 1);
    }
}

__global__ __launch_bounds__(256) void scan1_k(const int* __restrict__ deg,
                                               int* __restrict__ row_start,
                                               int* __restrict__ bsums,
                                               float* __restrict__ dinv) {
    __shared__ int sm[256];
    int tid = threadIdx.x;
    int i = blockIdx.x * 256 + tid;
    int v = (i < N_NODES) ? deg[i] : 0;
    if (i < N_NODES) dinv[i] = rsqrtf((float)(v + 1));
    sm[tid] = v;
    __syncthreads();
    #pragma unroll
    for (int off = 1; off < 256; off <<= 1) {
        int t = (tid >= off) ? sm[tid - off] : 0;
        __syncthreads();
        sm[tid] += t;
        __syncthreads();
    }
    if (i < N_NODES) row_start[i] = sm[tid] - v;
    if (tid == 255) bsums[blockIdx.x] = sm[255];
}

__global__ __launch_bounds__(256) void scan2_k(int* __restrict__ bsums, int nb) {
    __shared__ int sm[256];
    int tid = threadIdx.x;
    int v = (tid < nb) ? bsums[tid] : 0;
    sm[tid] = v;
    __syncthreads();
    #pragma unroll
    for (int off = 1; off < 256; off <<= 1) {
        int t = (tid >= off) ? sm[tid - off] : 0;
        __syncthreads();
        sm[tid] += t;
        __syncthreads();
    }
    if (tid < nb) bsums[tid] = sm[tid] - v;
}

__global__ __launch_bounds__(256) void scan3_k(int* __restrict__ row_start,
                                               const int* __restrict__ bsums) {
    int i = blockIdx.x * 256 + threadIdx.x;
    if (i < N_NODES) row_start[i] += bsums[blockIdx.x];
    if (i == 0) row_start[N_NODES] = N_EDGES;
}

__global__ __launch_bounds__(256) void fill_k(const int* __restrict__ ei,
                                              const int* __restrict__ row_start,
                                              int* __restrict__ cursor,
                                              const float* __restrict__ dinv,
                                              int2* __restrict__ csr_sw) {
    int e = blockIdx.x * 256 + threadIdx.x;
    if (e < N_EDGES) {
        int s = ei[e];
        int d = ei[N_EDGES + e];
        if ((unsigned)d < N_NODES && (unsigned)s < N_NODES) {
            int pos = row_start[d] + atomicAdd(&cursor[d], 1);
            if ((unsigned)pos < N_EDGES)
                csr_sw[pos] = make_int2(s, __float_as_int(dinv[s]));
        }
    }
}

// ---------------------------------------------------------------------------
// fp32 GEMM, whole-B-in-LDS; C written in SLICED layout [slice][node][16].
// ---------------------------------------------------------------------------
template <int N>
__global__ __launch_bounds__(256, 4) void gemm_blds(const float* __restrict__ A,
                                                    const float* __restrict__ B,
                                                    float* __restrict__ Cs, int M) {
    constexpr int K = 128, BM = 64, BN = 64, PAD = 4;
    __shared__ float Bs[K][BN + PAD];

    const int tid = threadIdx.x;
    const int nBase = blockIdx.y * BN;

    #pragma unroll
    for (int p = 0; p < 8; ++p) {
        int fi = tid + p * 256;
        int row = fi >> 4;
        int c4 = (fi & 15) * 4;
        float4 t = *(const float4*)&B[(size_t)row * N + nBase + c4];
        *(float4*)&Bs[row][c4] = t;
    }
    __syncthreads();

    const int tx = tid & 15, ty = tid >> 4;
    const int m0 = blockIdx.x * BM + ty * 4;
    const int n0 = tx * 4;

    const float* A0 = A + (size_t)(m0 + 0 < M ? m0 + 0 : M - 1) * K;
    const float* A1 = A + (size_t)(m0 + 1 < M ? m0 + 1 : M - 1) * K;
    const float* A2 = A + (size_t)(m0 + 2 < M ? m0 + 2 : M - 1) * K;
    const float* A3 = A + (size_t)(m0 + 3 < M ? m0 + 3 : M - 1) * K;

    float acc[4][4] = {};

    #pragma unroll 4
    for (int kq = 0; kq < K / 4; ++kq) {
        float4 a0 = *(const float4*)&A0[kq * 4];
        float4 a1 = *(const float4*)&A1[kq * 4];
        float4 a2 = *(const float4*)&A2[kq * 4];
        float4 a3 = *(const float4*)&A3[kq * 4];
        #pragma unroll
        for (int kk = 0; kk < 4; ++kk) {
            int k = kq * 4 + kk;
            float4 bv = *(const float4*)&Bs[k][n0];
            float av0 = kk == 0 ? a0.x : kk == 1 ? a0.y : kk == 2 ? a0.z : a0.w;
            float av1 = kk == 0 ? a1.x : kk == 1 ? a1.y : kk == 2 ? a1.z : a1.w;
            float av2 = kk == 0 ? a2.x : kk == 1 ? a2.y : kk == 2 ? a2.z : a2.w;
            float av3 = kk == 0 ? a3.x : kk == 1 ? a3.y : kk == 2 ? a3.z : a3.w;
            acc[0][0] = fmaf(av0, bv.x, acc[0][0]);
            acc[0][1] = fmaf(av0, bv.y, acc[0][1]);
            acc[0][2] = fmaf(av0, bv.z, acc[0][2]);
            acc[0][3] = fmaf(av0, bv.w, acc[0][3]);
            acc[1][0] = fmaf(av1, bv.x, acc[1][0]);
            acc[1][1] = fmaf(av1, bv.y, acc[1][1]);
            acc[1][2] = fmaf(av1, bv.z, acc[1][2]);
            acc[1][3] = fmaf(av1, bv.w, acc[1][3]);
            acc[2][0] = fmaf(av2, bv.x, acc[2][0]);
            acc[2][1] = fmaf(av2, bv.y, acc[2][1]);
            acc[2][2] = fmaf(av2, bv.z, acc[2][2]);
            acc[2][3] = fmaf(av2, bv.w, acc[2][3]);
            acc[3][0] = fmaf(av3, bv.x, acc[3][0]);
            acc[3][1] = fmaf(av3, bv.y, acc[3][1]);
            acc[3][2] = fmaf(av3, bv.z, acc[3][2]);
            acc[3][3] = fmaf(av3, bv.w, acc[3][3]);
        }
    }

    const int col0 = nBase + n0;
    const int slice = col0 >> 4;
    const int c15 = col0 & 15;
    #pragma unroll
    for (int i = 0; i < 4; ++i) {
        int row = blockIdx.x * BM + ty * 4 + i;
        if (row < M) {
            *(float4*)&Cs[(((size_t)slice * N_NODES + row) << 4) + c15] =
                make_float4(acc[i][0], acc[i][1], acc[i][2], acc[i][3]);
        }
    }
}

// ---------------------------------------------------------------------------
// XCD-pinned sliced aggregation, 4-deep MLP inner loop.
// Queue q -> slice q%SLICES, node-range q/SLICES. Wave: 4 edge-groups x 16
// scalar lanes. Fast path: 16 edges/iter, 4 independent gathers in flight.
// ---------------------------------------------------------------------------
template <int F, int SLICES, bool RELU>
__global__ __launch_bounds__(256) void agg_sliced_k(const float* __restrict__ h_s,
                                                    const float* __restrict__ dinv,
                                                    const int* __restrict__ row_start,
                                                    const int2* __restrict__ csr_sw,
                                                    const float* __restrict__ bias,
                                                    float* __restrict__ out,
                                                    int* __restrict__ qctr) {
    constexpr int NQ = 8;
    constexpr int CH = 64;
    constexpr int HALVES = NQ / SLICES;
    constexpr int NPQ = N_NODES / HALVES;
    constexpr int NCHUNK = (NPQ + CH - 1) / CH;

    __shared__ int sm_chunk;

    int xcd;
    asm volatile("s_getreg_b32 %0, hwreg(HW_REG_XCC_ID)" : "=s"(xcd));
    xcd &= 7;

    const int wv = threadIdx.x >> 6;
    const int lane = threadIdx.x & 63;
    const int g = lane >> 4;      // edge group 0..3
    const int c = lane & 15;      // col within slice

    for (int qi = 0; qi < NQ; ++qi) {
        const int q = (xcd + qi) & (NQ - 1);
        const int slice = q % SLICES;
        const int nbase = (q / SLICES) * NPQ;
        const float* hS = h_s + ((size_t)slice * N_NODES << 4) + c;
        const float bc = bias[slice * 16 + c];

        while (true) {
            if (threadIdx.x == 0) sm_chunk = atomicAdd(&qctr[q], 1);
            __syncthreads();
            const int chunk = sm_chunk;
            __syncthreads();
            if (chunk >= NCHUNK) break;

            const int vend = min(nbase + (chunk + 1) * CH, nbase + NPQ);
            for (int v = nbase + chunk * CH + wv; v < vend; v += 4) {
                const float dv = dinv[v];
                float acc = (g == 0) ? dv * hS[(size_t)v << 4] : 0.f;
                const int e0 = row_start[v], e1 = row_start[v + 1];
                for (int e = e0; e < e1; e += 64) {
                    const int cnt = min(64, e1 - e);
                    const int c1 = cnt - 1;
                    int s = 0; float w = 0.f;
                    if (lane < cnt) {
                        int2 p = csr_sw[e + lane];
                        s = p.x; w = __int_as_float(p.y);
                    }
                    int j = 0;
                    // fast path: 16 edges/iter, 4 gathers in flight
                    for (; j + 16 <= cnt; j += 16) {
                        const int i0 = j + g, i1 = j + g + 4,
                                  i2 = j + g + 8, i3 = j + g + 12;
                        const int ss0 = __shfl(s, i0), ss1 = __shfl(s, i1),
                                  ss2 = __shfl(s, i2), ss3 = __shfl(s, i3);
                        const float ww0 = __shfl(w, i0), ww1 = __shfl(w, i1),
                                    ww2 = __shfl(w, i2), ww3 = __shfl(w, i3);
                        const float t0 = hS[(size_t)ss0 << 4];
                        const float t1 = hS[(size_t)ss1 << 4];
                        const float t2 = hS[(size_t)ss2 << 4];
                        const float t3 = hS[(size_t)ss3 << 4];
                        acc = fmaf(ww0, t0, acc);
                        acc = fmaf(ww1, t1, acc);
                        acc = fmaf(ww2, t2, acc);
                        acc = fmaf(ww3, t3, acc);
                    }
                    // masked tail
                    for (; j < cnt; j += 4) {
                        const int idx = j + g;
                        const int i0 = min(idx, c1);
                        const int ss = __shfl(s, i0);
                        float ww = __shfl(w, i0);
                        if (idx >= cnt) ww = 0.f;
                        acc = fmaf(ww, hS[(size_t)ss << 4], acc);
                    }
                }
                acc += __shfl(acc, lane + 32);
                acc += __shfl(acc, lane + 16);
                if (g == 0) {
                    float o = dv * acc + bc;
                    if (RELU) o = fmaxf(o, 0.f);
                    out[(size_t)v * F + slice * 16 + c] = o;
                }
            }
        }
    }
}

extern "C" void kernel_launch(void* const* d_in, const int* in_sizes, int n_in,
                              void* d_out, int out_size, void* d_ws, size_t ws_size,
                              hipStream_t stream) {
    const float* x        = (const float*)d_in[0];   // [50000,128]
    const float* W1       = (const float*)d_in[1];   // [128,128]
    const float* b1       = (const float*)d_in[2];   // [128]
    const float* W2       = (const float*)d_in[3];   // [128,64]
    const float* b2       = (const float*)d_in[4];   // [64]
    const int*   ei       = (const int*)d_in[5];     // [2,800000] int32
    float* out = (float*)d_out;                      // [50000,64]

    char* ws = (char*)d_ws;
    int*   deg       = (int*)(ws + OFF_DEG);
    int*   cursor    = (int*)(ws + OFF_CUR);
    int*   qc1       = (int*)(ws + OFF_QC1);
    int*   qc2       = (int*)(ws + OFF_QC2);
    int*   row_start = (int*)(ws + OFF_ROW);
    int*   bsums     = (int*)(ws + OFF_BS);
    float* dinv      = (float*)(ws + OFF_DINV);
    int2*  csr_sw    = (int2*)(ws + OFF_SW);
    float* h1s       = (float*)(ws + OFF_H1);
    float* out1      = (float*)(ws + OFF_OUT1);
    float* h2s       = (float*)(ws + OFF_H1);  // reuse

    hipMemsetAsync(ws + OFF_DEG, 0, OFF_ROW - OFF_DEG, stream);

    const int nbE = (N_EDGES + 255) / 256;
    const int nbN = (N_NODES + 255) / 256;

    count_deg_k<<<nbE, 256, 0, stream>>>(ei, deg);
    scan1_k<<<nbN, 256, 0, stream>>>(deg, row_start, bsums, dinv);
    scan2_k<<<1, 256, 0, stream>>>(bsums, nbN);
    scan3_k<<<nbN, 256, 0, stream>>>(row_start, bsums);
    fill_k<<<nbE, 256, 0, stream>>>(ei, row_start, cursor, dinv, csr_sw);

    const int mBlocks = (N_NODES + 63) / 64;   // 782
    const int PERSIST = 2048;                  // 8 blocks/CU

    gemm_blds<128><<<dim3(mBlocks, 2), 256, 0, stream>>>(x, W1, h1s, N_NODES);
    agg_sliced_k<128, 8, true><<<PERSIST, 256, 0, stream>>>(h1s, dinv, row_start, csr_sw, b1, out1, qc1);
    gemm_blds<64><<<dim3(mBlocks, 1), 256, 0, stream>>>(out1, W2, h2s, N_NODES);
    agg_sliced_k<64, 4, false><<<PERSIST, 256, 0, stream>>>(h2s, dinv, row_start, csr_sw, b2, out, qc2);
}

// Round 15
// 244.500 us; speedup vs baseline: 3.0608x; 2.9689x over previous
//
#include <hip/hip_runtime.h>

// ---------------------------------------------------------------------------
// GCN 2-layer. N=50000, E=800000, F: 128 -> 128 -> 64.
// Settled model (R8-R14): pull-gather agg is bound by per-XCD L2 duplication:
//   FETCH = 7.3x h-table (each of 8 private L2s pulls ~whole table), drained
//   at ~3.3TB/s random-128B L3->L2 fill => ~57us/agg. Column-slicing + XCC
//   pinning cut FETCH to 70MB but ran 6x slower (per-slice edge reprocessing
//   + queue-protocol serialization) -- abandoned (R12-R14).
// R15: revert agg to R10 form (best measured). Purpose: surface gemm/CSR
//   dispatch costs in the profile for the next optimization target.
// ---------------------------------------------------------------------------

#define N_NODES 50000
#define N_EDGES 800000

// workspace layout (bytes)
static constexpr size_t OFF_DEG  = 0;         // int[50000]
static constexpr size_t OFF_CUR  = 200192;    // int[50000]
static constexpr size_t OFF_ROW  = 400384;    // int[50001]
static constexpr size_t OFF_BS   = 600576;    // int[256]
static constexpr size_t OFF_DINV = 601600;    // float[50000]
static constexpr size_t OFF_SW   = 801792;    // int2[800000] {src, w_bits}
static constexpr size_t OFF_H1   = 7201792;   // float[50000*128] (reused as h2)
static constexpr size_t OFF_OUT1 = 32801792;  // float[50000*128]
// total ~58.4 MB  (memset zeroes [0, OFF_ROW): deg+cursor)

__global__ __launch_bounds__(256) void count_deg_k(const int* __restrict__ ei,
                                                   int* __restrict__ deg) {
    int e = blockIdx.x * 256 + threadIdx.x;
    if (e < N_EDGES) {
        int d = ei[N_EDGES + e];
        if ((unsigned)d < N_NODES) atomicAdd(&deg[d], 1);
    }
}

__global__ __launch_bounds__(256) void scan1_k(const int* __restrict__ deg,
                                               int* __restrict__ row_start,
                                               int* __restrict__ bsums,
                                               float* __restrict__ dinv) {
    __shared__ int sm[256];
    int tid = threadIdx.x;
    int i = blockIdx.x * 256 + tid;
    int v = (i < N_NODES) ? deg[i] : 0;
    if (i < N_NODES) dinv[i] = rsqrtf((float)(v + 1));
    sm[tid] = v;
    __syncthreads();
    #pragma unroll
    for (int off = 1; off < 256; off <<= 1) {
        int t = (tid >= off) ? sm[tid - off] : 0;
        __syncthreads();
        sm[tid] += t;
        __syncthreads();
    }
    if (i < N_NODES) row_start[i] = sm[tid] - v;
    if (tid == 255) bsums[blockIdx.x] = sm[255];
}

__global__ __launch_bounds__(256) void scan2_k(int* __restrict__ bsums, int nb) {
    __shared__ int sm[256];
    int tid = threadIdx.x;
    int v = (tid < nb) ? bsums[tid] : 0;
    sm[tid] = v;
    __syncthreads();
    #pragma unroll
    for (int off = 1; off < 256; off <<= 1) {
        int t = (tid >= off) ? sm[tid - off] : 0;
        __syncthreads();
        sm[tid] += t;
        __syncthreads();
    }
    if (tid < nb) bsums[tid] = sm[tid] - v;
}

__global__ __launch_bounds__(256) void scan3_k(int* __restrict__ row_start,
                                               const int* __restrict__ bsums) {
    int i = blockIdx.x * 256 + threadIdx.x;
    if (i < N_NODES) row_start[i] += bsums[blockIdx.x];
    if (i == 0) row_start[N_NODES] = N_EDGES;
}

__global__ __launch_bounds__(256) void fill_k(const int* __restrict__ ei,
                                              const int* __restrict__ row_start,
                                              int* __restrict__ cursor,
                                              const float* __restrict__ dinv,
                                              int2* __restrict__ csr_sw) {
    int e = blockIdx.x * 256 + threadIdx.x;
    if (e < N_EDGES) {
        int s = ei[e];
        int d = ei[N_EDGES + e];
        if ((unsigned)d < N_NODES && (unsigned)s < N_NODES) {
            int pos = row_start[d] + atomicAdd(&cursor[d], 1);
            if ((unsigned)pos < N_EDGES)
                csr_sw[pos] = make_int2(s, __float_as_int(dinv[s]));
        }
    }
}

// ---------------------------------------------------------------------------
// fp32 GEMM, whole-B-in-LDS, row-major C. BM=64 x BN=64, 256 thr, 4x4 acc.
// ---------------------------------------------------------------------------
template <int N>
__global__ __launch_bounds__(256, 4) void gemm_blds(const float* __restrict__ A,
                                                    const float* __restrict__ B,
                                                    float* __restrict__ C, int M) {
    constexpr int K = 128, BM = 64, BN = 64, PAD = 4;
    __shared__ float Bs[K][BN + PAD];

    const int tid = threadIdx.x;
    const int nBase = blockIdx.y * BN;

    #pragma unroll
    for (int p = 0; p < 8; ++p) {
        int fi = tid + p * 256;
        int row = fi >> 4;
        int c4 = (fi & 15) * 4;
        float4 t = *(const float4*)&B[(size_t)row * N + nBase + c4];
        *(float4*)&Bs[row][c4] = t;
    }
    __syncthreads();

    const int tx = tid & 15, ty = tid >> 4;
    const int m0 = blockIdx.x * BM + ty * 4;
    const int n0 = tx * 4;

    const float* A0 = A + (size_t)(m0 + 0 < M ? m0 + 0 : M - 1) * K;
    const float* A1 = A + (size_t)(m0 + 1 < M ? m0 + 1 : M - 1) * K;
    const float* A2 = A + (size_t)(m0 + 2 < M ? m0 + 2 : M - 1) * K;
    const float* A3 = A + (size_t)(m0 + 3 < M ? m0 + 3 : M - 1) * K;

    float acc[4][4] = {};

    #pragma unroll 4
    for (int kq = 0; kq < K / 4; ++kq) {
        float4 a0 = *(const float4*)&A0[kq * 4];
        float4 a1 = *(const float4*)&A1[kq * 4];
        float4 a2 = *(const float4*)&A2[kq * 4];
        float4 a3 = *(const float4*)&A3[kq * 4];
        #pragma unroll
        for (int kk = 0; kk < 4; ++kk) {
            int k = kq * 4 + kk;
            float4 bv = *(const float4*)&Bs[k][n0];
            float av0 = kk == 0 ? a0.x : kk == 1 ? a0.y : kk == 2 ? a0.z : a0.w;
            float av1 = kk == 0 ? a1.x : kk == 1 ? a1.y : kk == 2 ? a1.z : a1.w;
            float av2 = kk == 0 ? a2.x : kk == 1 ? a2.y : kk == 2 ? a2.z : a2.w;
            float av3 = kk == 0 ? a3.x : kk == 1 ? a3.y : kk == 2 ? a3.z : a3.w;
            acc[0][0] = fmaf(av0, bv.x, acc[0][0]);
            acc[0][1] = fmaf(av0, bv.y, acc[0][1]);
            acc[0][2] = fmaf(av0, bv.z, acc[0][2]);
            acc[0][3] = fmaf(av0, bv.w, acc[0][3]);
            acc[1][0] = fmaf(av1, bv.x, acc[1][0]);
            acc[1][1] = fmaf(av1, bv.y, acc[1][1]);
            acc[1][2] = fmaf(av1, bv.z, acc[1][2]);
            acc[1][3] = fmaf(av1, bv.w, acc[1][3]);
            acc[2][0] = fmaf(av2, bv.x, acc[2][0]);
            acc[2][1] = fmaf(av2, bv.y, acc[2][1]);
            acc[2][2] = fmaf(av2, bv.z, acc[2][2]);
            acc[2][3] = fmaf(av2, bv.w, acc[2][3]);
            acc[3][0] = fmaf(av3, bv.x, acc[3][0]);
            acc[3][1] = fmaf(av3, bv.y, acc[3][1]);
            acc[3][2] = fmaf(av3, bv.z, acc[3][2]);
            acc[3][3] = fmaf(av3, bv.w, acc[3][3]);
        }
    }

    #pragma unroll
    for (int i = 0; i < 4; ++i) {
        int row = blockIdx.x * BM + ty * 4 + i;
        if (row < M) {
            *(float4*)&C[(size_t)row * N + nBase + n0] =
                make_float4(acc[i][0], acc[i][1], acc[i][2], acc[i][3]);
        }
    }
}

// ---------------------------------------------------------------------------
// Aggregation (R10 form, best measured): one wave per node, 8-deep MLP,
// packed int2 edge reads. out_v = d_v*(sum w_e h_s + d_v h_v) + b [, relu]
// ---------------------------------------------------------------------------
template <int F, bool RELU>
__global__ __launch_bounds__(256) void agg_k(const float* __restrict__ h,
                                             const float* __restrict__ dinv,
                                             const int* __restrict__ row_start,
                                             const int2* __restrict__ csr_sw,
                                             const float* __restrict__ bias,
                                             float* __restrict__ out) {
    constexpr int VEC = F / 64;  // 2 or 1
    int wid = (blockIdx.x * 256 + threadIdx.x) >> 6;
    int lane = threadIdx.x & 63;
    if (wid >= N_NODES) return;
    int v = wid;
    float dv = dinv[v];

    const float* hL = h + (size_t)lane * VEC;

    float acc0, acc1 = 0.f;
    {
        const float* hv = hL + (size_t)v * F;
        if constexpr (VEC == 2) {
            float2 t = *(const float2*)hv;
            acc0 = dv * t.x; acc1 = dv * t.y;
        } else {
            acc0 = dv * hv[0];
        }
    }

    int e0 = row_start[v], e1 = row_start[v + 1];
    for (int e = e0; e < e1; e += 64) {
        int cnt = min(64, e1 - e);
        int s = 0; float w = 0.f;
        if (lane < cnt) {
            int2 p = csr_sw[e + lane];
            s = p.x; w = __int_as_float(p.y);
        }
        int j = 0;
        for (; j + 8 <= cnt; j += 8) {
            int   ss0 = __shfl(s, j + 0), ss1 = __shfl(s, j + 1),
                  ss2 = __shfl(s, j + 2), ss3 = __shfl(s, j + 3),
                  ss4 = __shfl(s, j + 4), ss5 = __shfl(s, j + 5),
                  ss6 = __shfl(s, j + 6), ss7 = __shfl(s, j + 7);
            float ww0 = __shfl(w, j + 0), ww1 = __shfl(w, j + 1),
                  ww2 = __shfl(w, j + 2), ww3 = __shfl(w, j + 3),
                  ww4 = __shfl(w, j + 4), ww5 = __shfl(w, j + 5),
                  ww6 = __shfl(w, j + 6), ww7 = __shfl(w, j + 7);
            if constexpr (VEC == 2) {
                float2 t0 = *(const float2*)&hL[(size_t)ss0 * F];
                float2 t1 = *(const float2*)&hL[(size_t)ss1 * F];
                float2 t2 = *(const float2*)&hL[(size_t)ss2 * F];
                float2 t3 = *(const float2*)&hL[(size_t)ss3 * F];
                float2 t4 = *(const float2*)&hL[(size_t)ss4 * F];
                float2 t5 = *(const float2*)&hL[(size_t)ss5 * F];
                float2 t6 = *(const float2*)&hL[(size_t)ss6 * F];
                float2 t7 = *(const float2*)&hL[(size_t)ss7 * F];
                acc0 = fmaf(ww0, t0.x, acc0); acc1 = fmaf(ww0, t0.y, acc1);
                acc0 = fmaf(ww1, t1.x, acc0); acc1 = fmaf(ww1, t1.y, acc1);
                acc0 = fmaf(ww2, t2.x, acc0); acc1 = fmaf(ww2, t2.y, acc1);
                acc0 = fmaf(ww3, t3.x, acc0); acc1 = fmaf(ww3, t3.y, acc1);
                acc0 = fmaf(ww4, t4.x, acc0); acc1 = fmaf(ww4, t4.y, acc1);
                acc0 = fmaf(ww5, t5.x, acc0); acc1 = fmaf(ww5, t5.y, acc1);
                acc0 = fmaf(ww6, t6.x, acc0); acc1 = fmaf(ww6, t6.y, acc1);
                acc0 = fmaf(ww7, t7.x, acc0); acc1 = fmaf(ww7, t7.y, acc1);
            } else {
                float t0 = hL[(size_t)ss0 * F];
                float t1 = hL[(size_t)ss1 * F];
                float t2 = hL[(size_t)ss2 * F];
                float t3 = hL[(size_t)ss3 * F];
                float t4 = hL[(size_t)ss4 * F];
                float t5 = hL[(size_t)ss5 * F];
                float t6 = hL[(size_t)ss6 * F];
                float t7 = hL[(size_t)ss7 * F];
                acc0 = fmaf(ww0, t0, acc0);
                acc0 = fmaf(ww1, t1, acc0);
                acc0 = fmaf(ww2, t2, acc0);
                acc0 = fmaf(ww3, t3, acc0);
                acc0 = fmaf(ww4, t4, acc0);
                acc0 = fmaf(ww5, t5, acc0);
                acc0 = fmaf(ww6, t6, acc0);
                acc0 = fmaf(ww7, t7, acc0);
            }
        }
        for (; j < cnt; ++j) {
            int ss = __shfl(s, j);
            float ww = __shfl(w, j);
            if constexpr (VEC == 2) {
                float2 t = *(const float2*)&hL[(size_t)ss * F];
                acc0 = fmaf(ww, t.x, acc0); acc1 = fmaf(ww, t.y, acc1);
            } else {
                acc0 = fmaf(ww, hL[(size_t)ss * F], acc0);
            }
        }
    }

    if constexpr (VEC == 2) {
        float o0 = dv * acc0 + bias[lane * 2];
        float o1 = dv * acc1 + bias[lane * 2 + 1];
        if (RELU) { o0 = fmaxf(o0, 0.f); o1 = fmaxf(o1, 0.f); }
        *(float2*)&out[(size_t)v * F + lane * 2] = make_float2(o0, o1);
    } else {
        float o0 = dv * acc0 + bias[lane];
        if (RELU) o0 = fmaxf(o0, 0.f);
        out[(size_t)v * F + lane] = o0;
    }
}

extern "C" void kernel_launch(void* const* d_in, const int* in_sizes, int n_in,
                              void* d_out, int out_size, void* d_ws, size_t ws_size,
                              hipStream_t stream) {
    const float* x        = (const float*)d_in[0];   // [50000,128]
    const float* W1       = (const float*)d_in[1];   // [128,128]
    const float* b1       = (const float*)d_in[2];   // [128]
    const float* W2       = (const float*)d_in[3];   // [128,64]
    const float* b2       = (const float*)d_in[4];   // [64]
    const int*   ei       = (const int*)d_in[5];     // [2,800000] int32
    float* out = (float*)d_out;                      // [50000,64]

    char* ws = (char*)d_ws;
    int*   deg       = (int*)(ws + OFF_DEG);
    int*   cursor    = (int*)(ws + OFF_CUR);
    int*   row_start = (int*)(ws + OFF_ROW);
    int*   bsums     = (int*)(ws + OFF_BS);
    float* dinv      = (float*)(ws + OFF_DINV);
    int2*  csr_sw    = (int2*)(ws + OFF_SW);
    float* h1        = (float*)(ws + OFF_H1);
    float* out1      = (float*)(ws + OFF_OUT1);
    float* h2        = (float*)(ws + OFF_H1);  // reuse: h1 dead after agg1

    hipMemsetAsync(ws + OFF_DEG, 0, OFF_ROW - OFF_DEG, stream);

    const int nbE = (N_EDGES + 255) / 256;   // 3125
    const int nbN = (N_NODES + 255) / 256;   // 196

    count_deg_k<<<nbE, 256, 0, stream>>>(ei, deg);
    scan1_k<<<nbN, 256, 0, stream>>>(deg, row_start, bsums, dinv);
    scan2_k<<<1, 256, 0, stream>>>(bsums, nbN);
    scan3_k<<<nbN, 256, 0, stream>>>(row_start, bsums);
    fill_k<<<nbE, 256, 0, stream>>>(ei, row_start, cursor, dinv, csr_sw);

    const int mBlocks = (N_NODES + 63) / 64;   // 782
    gemm_blds<128><<<dim3(mBlocks, 2), 256, 0, stream>>>(x, W1, h1, N_NODES);
    agg_k<128, true><<<(N_NODES + 3) / 4, 256, 0, stream>>>(h1, dinv, row_start, csr_sw, b1, out1);
    gemm_blds<64><<<dim3(mBlocks, 1), 256, 0, stream>>>(out1, W2, h2, N_NODES);
    agg_k<64, false><<<(N_NODES + 3) / 4, 256, 0, stream>>>(h2, dinv, row_start, csr_sw, b2, out);
}

// Round 16
// 208.745 us; speedup vs baseline: 3.5850x; 1.1713x over previous
//
#include <hip/hip_runtime.h>
#include <hip/hip_fp16.h>

// ---------------------------------------------------------------------------
// GCN 2-layer. N=50000, E=800000, F: 128 -> 128 -> 64.
// Settled model (R8-R15): pull-gather agg bound by per-XCD L2 duplication:
//   FETCH = 7.3x gathered-table bytes, drained at ~3.3TB/s. Execution
//   restructures (slicing/pinning/queues, R12-R14) failed; table-size is the
//   remaining lever.
// R16: store gathered arrays z1=x@W1, z2=relu@W2 in FP16 (RNE, fp32 accum
//   everywhere). Table 25.6->12.8MB / 12.8->6.4MB => agg FETCH ~halves.
//   fp16 over bf16: 4x smaller mantissa error; |z|<=~6 well in range.
// ---------------------------------------------------------------------------

#define N_NODES 50000
#define N_EDGES 800000

// workspace layout (bytes)
static constexpr size_t OFF_DEG  = 0;         // int[50000]
static constexpr size_t OFF_CUR  = 200192;    // int[50000]
static constexpr size_t OFF_ROW  = 400384;    // int[50001]
static constexpr size_t OFF_BS   = 600576;    // int[256]
static constexpr size_t OFF_DINV = 601600;    // float[50000]
static constexpr size_t OFF_SW   = 801792;    // int2[800000] {src, w_bits}
static constexpr size_t OFF_Z    = 7201792;   // __half[50000*128] z1 (reused z2)
static constexpr size_t OFF_OUT1 = 20801792;  // float[50000*128]
// total ~46.4 MB  (memset zeroes [0, OFF_ROW): deg+cursor)

__global__ __launch_bounds__(256) void count_deg_k(const int* __restrict__ ei,
                                                   int* __restrict__ deg) {
    int e = blockIdx.x * 256 + threadIdx.x;
    if (e < N_EDGES) {
        int d = ei[N_EDGES + e];
        if ((unsigned)d < N_NODES) atomicAdd(&deg[d], 1);
    }
}

__global__ __launch_bounds__(256) void scan1_k(const int* __restrict__ deg,
                                               int* __restrict__ row_start,
                                               int* __restrict__ bsums,
                                               float* __restrict__ dinv) {
    __shared__ int sm[256];
    int tid = threadIdx.x;
    int i = blockIdx.x * 256 + tid;
    int v = (i < N_NODES) ? deg[i] : 0;
    if (i < N_NODES) dinv[i] = rsqrtf((float)(v + 1));
    sm[tid] = v;
    __syncthreads();
    #pragma unroll
    for (int off = 1; off < 256; off <<= 1) {
        int t = (tid >= off) ? sm[tid - off] : 0;
        __syncthreads();
        sm[tid] += t;
        __syncthreads();
    }
    if (i < N_NODES) row_start[i] = sm[tid] - v;
    if (tid == 255) bsums[blockIdx.x] = sm[255];
}

__global__ __launch_bounds__(256) void scan2_k(int* __restrict__ bsums, int nb) {
    __shared__ int sm[256];
    int tid = threadIdx.x;
    int v = (tid < nb) ? bsums[tid] : 0;
    sm[tid] = v;
    __syncthreads();
    #pragma unroll
    for (int off = 1; off < 256; off <<= 1) {
        int t = (tid >= off) ? sm[tid - off] : 0;
        __syncthreads();
        sm[tid] += t;
        __syncthreads();
    }
    if (tid < nb) bsums[tid] = sm[tid] - v;
}

__global__ __launch_bounds__(256) void scan3_k(int* __restrict__ row_start,
                                               const int* __restrict__ bsums) {
    int i = blockIdx.x * 256 + threadIdx.x;
    if (i < N_NODES) row_start[i] += bsums[blockIdx.x];
    if (i == 0) row_start[N_NODES] = N_EDGES;
}

__global__ __launch_bounds__(256) void fill_k(const int* __restrict__ ei,
                                              const int* __restrict__ row_start,
                                              int* __restrict__ cursor,
                                              const float* __restrict__ dinv,
                                              int2* __restrict__ csr_sw) {
    int e = blockIdx.x * 256 + threadIdx.x;
    if (e < N_EDGES) {
        int s = ei[e];
        int d = ei[N_EDGES + e];
        if ((unsigned)d < N_NODES && (unsigned)s < N_NODES) {
            int pos = row_start[d] + atomicAdd(&cursor[d], 1);
            if ((unsigned)pos < N_EDGES)
                csr_sw[pos] = make_int2(s, __float_as_int(dinv[s]));
        }
    }
}

// ---------------------------------------------------------------------------
// fp32 GEMM, whole-B-in-LDS; C stored as FP16 (RNE). BM=64 x BN=64, 4x4 acc.
// ---------------------------------------------------------------------------
template <int N>
__global__ __launch_bounds__(256, 4) void gemm_blds(const float* __restrict__ A,
                                                    const float* __restrict__ B,
                                                    __half* __restrict__ C, int M) {
    constexpr int K = 128, BM = 64, BN = 64, PAD = 4;
    __shared__ float Bs[K][BN + PAD];

    const int tid = threadIdx.x;
    const int nBase = blockIdx.y * BN;

    #pragma unroll
    for (int p = 0; p < 8; ++p) {
        int fi = tid + p * 256;
        int row = fi >> 4;
        int c4 = (fi & 15) * 4;
        float4 t = *(const float4*)&B[(size_t)row * N + nBase + c4];
        *(float4*)&Bs[row][c4] = t;
    }
    __syncthreads();

    const int tx = tid & 15, ty = tid >> 4;
    const int m0 = blockIdx.x * BM + ty * 4;
    const int n0 = tx * 4;

    const float* A0 = A + (size_t)(m0 + 0 < M ? m0 + 0 : M - 1) * K;
    const float* A1 = A + (size_t)(m0 + 1 < M ? m0 + 1 : M - 1) * K;
    const float* A2 = A + (size_t)(m0 + 2 < M ? m0 + 2 : M - 1) * K;
    const float* A3 = A + (size_t)(m0 + 3 < M ? m0 + 3 : M - 1) * K;

    float acc[4][4] = {};

    #pragma unroll 4
    for (int kq = 0; kq < K / 4; ++kq) {
        float4 a0 = *(const float4*)&A0[kq * 4];
        float4 a1 = *(const float4*)&A1[kq * 4];
        float4 a2 = *(const float4*)&A2[kq * 4];
        float4 a3 = *(const float4*)&A3[kq * 4];
        #pragma unroll
        for (int kk = 0; kk < 4; ++kk) {
            int k = kq * 4 + kk;
            float4 bv = *(const float4*)&Bs[k][n0];
            float av0 = kk == 0 ? a0.x : kk == 1 ? a0.y : kk == 2 ? a0.z : a0.w;
            float av1 = kk == 0 ? a1.x : kk == 1 ? a1.y : kk == 2 ? a1.z : a1.w;
            float av2 = kk == 0 ? a2.x : kk == 1 ? a2.y : kk == 2 ? a2.z : a2.w;
            float av3 = kk == 0 ? a3.x : kk == 1 ? a3.y : kk == 2 ? a3.z : a3.w;
            acc[0][0] = fmaf(av0, bv.x, acc[0][0]);
            acc[0][1] = fmaf(av0, bv.y, acc[0][1]);
            acc[0][2] = fmaf(av0, bv.z, acc[0][2]);
            acc[0][3] = fmaf(av0, bv.w, acc[0][3]);
            acc[1][0] = fmaf(av1, bv.x, acc[1][0]);
            acc[1][1] = fmaf(av1, bv.y, acc[1][1]);
            acc[1][2] = fmaf(av1, bv.z, acc[1][2]);
            acc[1][3] = fmaf(av1, bv.w, acc[1][3]);
            acc[2][0] = fmaf(av2, bv.x, acc[2][0]);
            acc[2][1] = fmaf(av2, bv.y, acc[2][1]);
            acc[2][2] = fmaf(av2, bv.z, acc[2][2]);
            acc[2][3] = fmaf(av2, bv.w, acc[2][3]);
            acc[3][0] = fmaf(av3, bv.x, acc[3][0]);
            acc[3][1] = fmaf(av3, bv.y, acc[3][1]);
            acc[3][2] = fmaf(av3, bv.z, acc[3][2]);
            acc[3][3] = fmaf(av3, bv.w, acc[3][3]);
        }
    }

    #pragma unroll
    for (int i = 0; i < 4; ++i) {
        int row = blockIdx.x * BM + ty * 4 + i;
        if (row < M) {
            __half2 h0 = __floats2half2_rn(acc[i][0], acc[i][1]);
            __half2 h1 = __floats2half2_rn(acc[i][2], acc[i][3]);
            uint2 st = make_uint2(*(unsigned*)&h0, *(unsigned*)&h1);
            *(uint2*)&C[(size_t)row * N + nBase + n0] = st;   // 8B aligned
        }
    }
}

// ---------------------------------------------------------------------------
// Aggregation: one wave per node, fp16 gathers (fp32 accum), 8-deep MLP,
// packed int2 edge reads. out_v = d_v*(sum w_e z_s + d_v z_v) + b [, relu]
// ---------------------------------------------------------------------------
template <int F, bool RELU>
__global__ __launch_bounds__(256) void agg_k(const __half* __restrict__ h,
                                             const float* __restrict__ dinv,
                                             const int* __restrict__ row_start,
                                             const int2* __restrict__ csr_sw,
                                             const float* __restrict__ bias,
                                             float* __restrict__ out) {
    constexpr int VEC = F / 64;  // 2 or 1
    int wid = (blockIdx.x * 256 + threadIdx.x) >> 6;
    int lane = threadIdx.x & 63;
    if (wid >= N_NODES) return;
    int v = wid;
    float dv = dinv[v];

    const __half* hL = h + (size_t)lane * VEC;

    float acc0, acc1 = 0.f;
    {
        if constexpr (VEC == 2) {
            float2 t = __half22float2(*(const __half2*)&hL[(size_t)v * F]);
            acc0 = dv * t.x; acc1 = dv * t.y;
        } else {
            acc0 = dv * __half2float(hL[(size_t)v * F]);
        }
    }

    int e0 = row_start[v], e1 = row_start[v + 1];
    for (int e = e0; e < e1; e += 64) {
        int cnt = min(64, e1 - e);
        int s = 0; float w = 0.f;
        if (lane < cnt) {
            int2 p = csr_sw[e + lane];
            s = p.x; w = __int_as_float(p.y);
        }
        int j = 0;
        for (; j + 8 <= cnt; j += 8) {
            int   ss0 = __shfl(s, j + 0), ss1 = __shfl(s, j + 1),
                  ss2 = __shfl(s, j + 2), ss3 = __shfl(s, j + 3),
                  ss4 = __shfl(s, j + 4), ss5 = __shfl(s, j + 5),
                  ss6 = __shfl(s, j + 6), ss7 = __shfl(s, j + 7);
            float ww0 = __shfl(w, j + 0), ww1 = __shfl(w, j + 1),
                  ww2 = __shfl(w, j + 2), ww3 = __shfl(w, j + 3),
                  ww4 = __shfl(w, j + 4), ww5 = __shfl(w, j + 5),
                  ww6 = __shfl(w, j + 6), ww7 = __shfl(w, j + 7);
            if constexpr (VEC == 2) {
                __half2 r0 = *(const __half2*)&hL[(size_t)ss0 * F];
                __half2 r1 = *(const __half2*)&hL[(size_t)ss1 * F];
                __half2 r2 = *(const __half2*)&hL[(size_t)ss2 * F];
                __half2 r3 = *(const __half2*)&hL[(size_t)ss3 * F];
                __half2 r4 = *(const __half2*)&hL[(size_t)ss4 * F];
                __half2 r5 = *(const __half2*)&hL[(size_t)ss5 * F];
                __half2 r6 = *(const __half2*)&hL[(size_t)ss6 * F];
                __half2 r7 = *(const __half2*)&hL[(size_t)ss7 * F];
                float2 t0 = __half22float2(r0), t1 = __half22float2(r1),
                       t2 = __half22float2(r2), t3 = __half22float2(r3),
                       t4 = __half22float2(r4), t5 = __half22float2(r5),
                       t6 = __half22float2(r6), t7 = __half22float2(r7);
                acc0 = fmaf(ww0, t0.x, acc0); acc1 = fmaf(ww0, t0.y, acc1);
                acc0 = fmaf(ww1, t1.x, acc0); acc1 = fmaf(ww1, t1.y, acc1);
                acc0 = fmaf(ww2, t2.x, acc0); acc1 = fmaf(ww2, t2.y, acc1);
                acc0 = fmaf(ww3, t3.x, acc0); acc1 = fmaf(ww3, t3.y, acc1);
                acc0 = fmaf(ww4, t4.x, acc0); acc1 = fmaf(ww4, t4.y, acc1);
                acc0 = fmaf(ww5, t5.x, acc0); acc1 = fmaf(ww5, t5.y, acc1);
                acc0 = fmaf(ww6, t6.x, acc0); acc1 = fmaf(ww6, t6.y, acc1);
                acc0 = fmaf(ww7, t7.x, acc0); acc1 = fmaf(ww7, t7.y, acc1);
            } else {
                float t0 = __half2float(hL[(size_t)ss0 * F]);
                float t1 = __half2float(hL[(size_t)ss1 * F]);
                float t2 = __half2float(hL[(size_t)ss2 * F]);
                float t3 = __half2float(hL[(size_t)ss3 * F]);
                float t4 = __half2float(hL[(size_t)ss4 * F]);
                float t5 = __half2float(hL[(size_t)ss5 * F]);
                float t6 = __half2float(hL[(size_t)ss6 * F]);
                float t7 = __half2float(hL[(size_t)ss7 * F]);
                acc0 = fmaf(ww0, t0, acc0);
                acc0 = fmaf(ww1, t1, acc0);
                acc0 = fmaf(ww2, t2, acc0);
                acc0 = fmaf(ww3, t3, acc0);
                acc0 = fmaf(ww4, t4, acc0);
                acc0 = fmaf(ww5, t5, acc0);
                acc0 = fmaf(ww6, t6, acc0);
                acc0 = fmaf(ww7, t7, acc0);
            }
        }
        for (; j < cnt; ++j) {
            int ss = __shfl(s, j);
            float ww = __shfl(w, j);
            if constexpr (VEC == 2) {
                float2 t = __half22float2(*(const __half2*)&hL[(size_t)ss * F]);
                acc0 = fmaf(ww, t.x, acc0); acc1 = fmaf(ww, t.y, acc1);
            } else {
                acc0 = fmaf(ww, __half2float(hL[(size_t)ss * F]), acc0);
            }
        }
    }

    if constexpr (VEC == 2) {
        float o0 = dv * acc0 + bias[lane * 2];
        float o1 = dv * acc1 + bias[lane * 2 + 1];
        if (RELU) { o0 = fmaxf(o0, 0.f); o1 = fmaxf(o1, 0.f); }
        *(float2*)&out[(size_t)v * F + lane * 2] = make_float2(o0, o1);
    } else {
        float o0 = dv * acc0 + bias[lane];
        if (RELU) o0 = fmaxf(o0, 0.f);
        out[(size_t)v * F + lane] = o0;
    }
}

extern "C" void kernel_launch(void* const* d_in, const int* in_sizes, int n_in,
                              void* d_out, int out_size, void* d_ws, size_t ws_size,
                              hipStream_t stream) {
    const float* x        = (const float*)d_in[0];   // [50000,128]
    const float* W1       = (const float*)d_in[1];   // [128,128]
    const float* b1       = (const float*)d_in[2];   // [128]
    const float* W2       = (const float*)d_in[3];   // [128,64]
    const float* b2       = (const float*)d_in[4];   // [64]
    const int*   ei       = (const int*)d_in[5];     // [2,800000] int32
    float* out = (float*)d_out;                      // [50000,64]

    char* ws = (char*)d_ws;
    int*    deg       = (int*)(ws + OFF_DEG);
    int*    cursor    = (int*)(ws + OFF_CUR);
    int*    row_start = (int*)(ws + OFF_ROW);
    int*    bsums     = (int*)(ws + OFF_BS);
    float*  dinv      = (float*)(ws + OFF_DINV);
    int2*   csr_sw    = (int2*)(ws + OFF_SW);
    __half* z         = (__half*)(ws + OFF_Z);       // z1, reused as z2
    float*  out1      = (float*)(ws + OFF_OUT1);

    hipMemsetAsync(ws + OFF_DEG, 0, OFF_ROW - OFF_DEG, stream);

    const int nbE = (N_EDGES + 255) / 256;   // 3125
    const int nbN = (N_NODES + 255) / 256;   // 196

    count_deg_k<<<nbE, 256, 0, stream>>>(ei, deg);
    scan1_k<<<nbN, 256, 0, stream>>>(deg, row_start, bsums, dinv);
    scan2_k<<<1, 256, 0, stream>>>(bsums, nbN);
    scan3_k<<<nbN, 256, 0, stream>>>(row_start, bsums);
    fill_k<<<nbE, 256, 0, stream>>>(ei, row_start, cursor, dinv, csr_sw);

    const int mBlocks = (N_NODES + 63) / 64;   // 782
    gemm_blds<128><<<dim3(mBlocks, 2), 256, 0, stream>>>(x, W1, z, N_NODES);
    agg_k<128, true><<<(N_NODES + 3) / 4, 256, 0, stream>>>(z, dinv, row_start, csr_sw, b1, out1);
    gemm_blds<64><<<dim3(mBlocks, 1), 256, 0, stream>>>(out1, W2, z, N_NODES);
    agg_k<64, false><<<(N_NODES + 3) / 4, 256, 0, stream>>>(z, dinv, row_start, csr_sw, b2, out);
}